// Round 5
// baseline (273.400 us; speedup 1.0000x reference)
//
#include <hip/hip_runtime.h>
#include <hip/hip_bf16.h>
#include <math.h>

// MambaBlock v13: v12 +
//  (a) k_gemm2 full-192-d per block (grid 512x1): hid read once, not twice
//  (b) k_gemm1 grid swapped to (6,256): blocks sharing an xn2 A-tile are
//      dispatch-adjacent -> L2 reuse of the 6x re-read
//  (c) k_scan2 merged into k_conv (blockIdx.x==192 plane), launched after
//      k_proj: the 8-block serial scan hides under conv's 1536 blocks
// Dispatches: 7 -> 6.

#define DEV static __device__ __forceinline__

constexpr int Bn = 8, Dm = 192, Ln = 4096, Sn = 64, Hd = 768;

typedef __attribute__((ext_vector_type(8))) short bf16x8;
typedef __attribute__((ext_vector_type(4))) float f32x4;

DEV float wave_sum(float v) {
#pragma unroll
  for (int off = 1; off < 64; off <<= 1) v += __shfl_xor(v, off);
  return v;
}

DEV short f2b(float x) {
  __hip_bfloat16 h = __float2bfloat16(x);
  return *(short*)&h;
}

DEV float b2f(short x) {
  __hip_bfloat16 h = *(__hip_bfloat16*)&x;
  return __bfloat162float(h);
}

// ---- K1: prep = transpose+ln1+ssm_ln (y<8) fused with weight->bf16 (y==8) --
__global__ __launch_bounds__(256) void k_prep(
    const float* __restrict__ x, const float* __restrict__ g1, const float* __restrict__ b1,
    const float* __restrict__ g2, const float* __restrict__ b2,
    short* __restrict__ xnb, short* __restrict__ xln1b,
    const float* __restrict__ dt_w, const float* __restrict__ B_w,
    const float* __restrict__ C_w, const float* __restrict__ xp_w,
    const float* __restrict__ out_w, const float* __restrict__ w1,
    const float* __restrict__ w2, short* __restrict__ wb) {
  __shared__ __align__(16) float tile[Dm * 65];
  int tid = threadIdx.x;
  if (blockIdx.y == 8) {
    for (int i = blockIdx.x * 256 + tid; i < 89088; i += 64 * 256) {
      const float4* src;
      if (i < 3072)       src = (const float4*)dt_w + i;
      else if (i < 6144)  src = (const float4*)B_w + (i - 3072);
      else if (i < 9216)  src = (const float4*)C_w + (i - 6144);
      else if (i < 12288) src = (const float4*)xp_w + (i - 9216);
      else if (i < 15360) src = (const float4*)out_w + (i - 12288);
      else if (i < 52224) src = (const float4*)w1 + (i - 15360);
      else                src = (const float4*)w2 + (i - 52224);
      float4 v = *src;
      int o = i * 4;
      wb[o] = f2b(v.x); wb[o + 1] = f2b(v.y); wb[o + 2] = f2b(v.z); wb[o + 3] = f2b(v.w);
    }
    return;
  }
  int b = blockIdx.y, l0 = blockIdx.x * 64;
  const float* xb = x + (size_t)b * Dm * Ln;
  for (int i = tid; i < Dm * 16; i += 256) {
    int d = i >> 4, l4 = (i & 15) << 2;
    float4 v = *(const float4*)&xb[d * Ln + l0 + l4];
    tile[d * 65 + l4]     = v.x; tile[d * 65 + l4 + 1] = v.y;
    tile[d * 65 + l4 + 2] = v.z; tile[d * 65 + l4 + 3] = v.w;
  }
  __syncthreads();
  int lane = tid & 63, wv = tid >> 6;
  float ga0 = g1[lane], ga1 = g1[lane + 64], ga2 = g1[lane + 128];
  float bb0 = b1[lane], bb1 = b1[lane + 64], bb2 = b1[lane + 128];
  float gc0 = g2[lane], gc1 = g2[lane + 64], gc2 = g2[lane + 128];
  float bc0 = b2[lane], bc1 = b2[lane + 64], bc2 = b2[lane + 128];
  for (int li = wv; li < 64; li += 4) {
    float v0 = tile[lane * 65 + li], v1 = tile[(lane + 64) * 65 + li], v2 = tile[(lane + 128) * 65 + li];
    float s  = wave_sum(v0 + v1 + v2);
    float sq = wave_sum(v0 * v0 + v1 * v1 + v2 * v2);
    float m = s * (1.f / 192.f);
    float inv = rsqrtf(sq * (1.f / 192.f) - m * m + 1e-5f);
    float y0 = (v0 - m) * inv * ga0 + bb0;
    float y1 = (v1 - m) * inv * ga1 + bb1;
    float y2 = (v2 - m) * inv * ga2 + bb2;
    float s2  = wave_sum(y0 + y1 + y2);
    float sq2 = wave_sum(y0 * y0 + y1 * y1 + y2 * y2);
    float m2 = s2 * (1.f / 192.f);
    float inv2 = rsqrtf(sq2 * (1.f / 192.f) - m2 * m2 + 1e-5f);
    size_t base = ((size_t)b * Ln + l0 + li) * Dm;
    xln1b[base + lane]       = f2b(y0);
    xln1b[base + lane + 64]  = f2b(y1);
    xln1b[base + lane + 128] = f2b(y2);
    xnb[base + lane]       = f2b((y0 - m2) * inv2 * gc0 + bc0);
    xnb[base + lane + 64]  = f2b((y1 - m2) * inv2 * gc1 + bc1);
    xnb[base + lane + 128] = f2b((y2 - m2) * inv2 * gc2 + bc2);
  }
}

// ---- K2: MFMA proj GEMM + packed SSM epilogue + fused scan phase 1 ---------
__global__ __launch_bounds__(256) void k_proj(
    const short* __restrict__ xnb, const short* __restrict__ wcat,
    const float* __restrict__ dt_b, const float* __restrict__ xp_b,
    const float* __restrict__ A_log, float* __restrict__ aA, unsigned* __restrict__ bxc,
    float* __restrict__ sums) {
  __shared__ __align__(16) short As[64 * 72];
  __shared__ __align__(16) short Bs[256 * 72];
  int m0 = blockIdx.x * 64, tid = threadIdx.x;
  int lane = tid & 63, l16 = lane & 15, quad = lane >> 4, w = tid >> 6;
  f32x4 acc[16] = {};
  for (int kt = 0; kt < 3; kt++) {
    int kb = kt * 64;
    for (int i = tid; i < 512; i += 256) {
      int row = i >> 3, c8 = (i & 7) * 8;
      *(float4*)&As[row * 72 + c8] = *(const float4*)&xnb[(size_t)(m0 + row) * 192 + kb + c8];
    }
    for (int i = tid; i < 2048; i += 256) {
      int row = i >> 3, c8 = (i & 7) * 8;
      *(float4*)&Bs[row * 72 + c8] = *(const float4*)&wcat[(size_t)row * 192 + kb + c8];
    }
    __syncthreads();
#pragma unroll
    for (int ks = 0; ks < 2; ks++) {
      int ko = ks * 32 + quad * 8;
      bf16x8 a0 = *(const bf16x8*)&As[(w * 16 + l16) * 72 + ko];
#pragma unroll
      for (int nh = 0; nh < 2; nh++) {
        bf16x8 bfr[8];
#pragma unroll
        for (int j = 0; j < 8; j++) bfr[j] = *(const bf16x8*)&Bs[((nh * 8 + j) * 16 + l16) * 72 + ko];
#pragma unroll
        for (int j = 0; j < 8; j++)
          acc[nh * 8 + j] = __builtin_amdgcn_mfma_f32_16x16x32_bf16(a0, bfr[j], acc[nh * 8 + j], 0, 0, 0);
      }
    }
    __syncthreads();
  }
  float* aAs = (float*)Bs;        // [64][65] f32
  float* bxs = aAs + 64 * 65;     // [64][65] f32
  float Av[4], dtbv[4], xpbv[4];
#pragma unroll
  for (int ni = 0; ni < 4; ni++) {
    int s = ni * 16 + l16;
    Av[ni] = -expf(A_log[s]); dtbv[ni] = dt_b[s]; xpbv[ni] = xp_b[s];
  }
#pragma unroll
  for (int r = 0; r < 4; r++) {
    int lm = w * 16 + quad * 4 + r;
    int m = m0 + lm;
#pragma unroll
    for (int ni = 0; ni < 4; ni++) {
      int s = ni * 16 + l16;
      float z = acc[ni][r] + dtbv[ni];
      float sp = (z > 20.f) ? z : log1pf(expf(z));
      float delta = sp * 0.01f + 0.0001f;
      float bt  = acc[ni + 4][r];
      float ct  = acc[ni + 8][r];
      float xpv = acc[ni + 12][r] + xpbv[ni];
      float dA = fminf(fmaxf(delta * Av[ni], -10.f), -0.0001f);
      float Ae = fminf(fmaxf(expf(dA), 0.001f), 0.999f) + 1e-10f;
      short bxh = f2b(delta * bt * xpv);
      aA[(size_t)m * 64 + s] = Ae;
      unsigned pk = (unsigned)(unsigned short)bxh
                  | ((unsigned)(unsigned short)f2b(ct) << 16);
      bxc[(size_t)m * 64 + s] = pk;
      aAs[lm * 65 + s] = Ae;
      bxs[lm * 65 + s] = b2f(bxh);
    }
  }
  __syncthreads();
  int s = tid & 63, seg = tid >> 6, chunk = seg >> 1, sub = seg & 1;
  bool first = ((m0 & 4095) == 0) && (chunk == 0) && (sub == 0);
  float P = 1.f, H = 0.f;
  int base = chunk * 32 + sub * 16;
#pragma unroll
  for (int j = 0; j < 16; j++) {
    float a  = aAs[(base + j) * 65 + s];
    float bx = bxs[(base + j) * 65 + s];
    if (first && j == 0) { P = a; H = bx; }
    else { P *= a; H = a * (H + bx); }
  }
  float* partP = (float*)As;
  float* partH = partP + 256;
  partP[seg * 64 + s] = P; partH[seg * 64 + s] = H;
  __syncthreads();
  if (tid < 128) {
    int c = tid >> 6;
    float p0 = partP[(c * 2) * 64 + s], p1 = partP[(c * 2 + 1) * 64 + s];
    float h0 = partH[(c * 2) * 64 + s], h1 = partH[(c * 2 + 1) * 64 + s];
    int ci = (m0 >> 12) * 128 + ((m0 & 4095) >> 5) + c;
    sums[(ci * 2 + 0) * 64 + s] = p0 * p1;
    sums[(ci * 2 + 1) * 64 + s] = p1 * h0 + h1;
  }
}

// ---- K3: conv (x<192) + scan phase 2 (x==192) merged ----------------------
// conv: depthwise 3x3 + BN -> xr1 = x + a_loc*x_local (NCHW)
// scan2: 4-way chain split + affine prefix, one 256-thr block per batch
__global__ __launch_bounds__(256) void k_conv(
    const float* __restrict__ x, const float* __restrict__ dw,
    const float* __restrict__ bn_g, const float* __restrict__ bn_b,
    const float* __restrict__ bn_rm, const float* __restrict__ bn_rv,
    const float* __restrict__ a_loc, float* __restrict__ xr,
    const float* __restrict__ sums, float* __restrict__ carries) {
  __shared__ __align__(16) float xs[64 * 64];
  int tid = threadIdx.x;
  if (blockIdx.x == 192) {
    // ---- scan2 ----
    float* Pp = xs;            // [4][64]
    float* Hp = xs + 256;      // [4][64]
    int b = blockIdx.y, s = tid & 63, q = tid >> 6;
    float P = 1.f, H = 0.f;
#pragma unroll 4
    for (int j = 0; j < 32; j++) {
      int ci = b * 128 + q * 32 + j;
      float a = sums[(ci * 2 + 0) * 64 + s];
      float h = sums[(ci * 2 + 1) * 64 + s];
      P *= a; H = a * H + h;
    }
    Pp[q * 64 + s] = P; Hp[q * 64 + s] = H;
    __syncthreads();
    float cur = 0.f;
    for (int qq = 0; qq < q; qq++) cur = Pp[qq * 64 + s] * cur + Hp[qq * 64 + s];
#pragma unroll 4
    for (int j = 0; j < 32; j++) {
      int ci = b * 128 + q * 32 + j;
      carries[ci * 64 + s] = cur;
      float a = sums[(ci * 2 + 0) * 64 + s];
      float h = sums[(ci * 2 + 1) * 64 + s];
      cur = a * cur + h;
    }
    return;
  }
  int d = blockIdx.x, b = blockIdx.y;
  const float* xp = x + ((size_t)b * Dm + d) * Ln;
  for (int i = tid; i < 1024; i += 256) ((float4*)xs)[i] = ((const float4*)xp)[i];
  __syncthreads();
  float w[9];
#pragma unroll
  for (int k = 0; k < 9; k++) w[k] = dw[d * 9 + k];
  float scale = bn_g[d] * rsqrtf(bn_rv[d] + 1e-5f);
  float rm = bn_rm[d], bb = bn_b[d];
  float al = a_loc[0];
  float* xo = xr + ((size_t)b * Dm + d) * Ln;
  for (int i = tid; i < 4096; i += 256) {
    int h = i >> 6, wc = i & 63;
    float acc = 0.f;
#pragma unroll
    for (int kh = 0; kh < 3; kh++) {
      int hh = h + kh - 1;
      if (hh < 0 || hh >= 64) continue;
#pragma unroll
      for (int kw = 0; kw < 3; kw++) {
        int ww2 = wc + kw - 1;
        if (ww2 < 0 || ww2 >= 64) continue;
        acc += xs[hh * 64 + ww2] * w[kh * 3 + kw];
      }
    }
    float xl = (acc - rm) * scale + bb;
    xo[i] = xs[i] + al * xl;
  }
}

// ---- K4: fused scan replay + out-proj + combine (RMW xr) + LN2 -> xn2 ------
__global__ __launch_bounds__(256) void k_out(
    const float* __restrict__ aA, const unsigned* __restrict__ bxc,
    const float* __restrict__ carries,
    const short* __restrict__ owb, const float* __restrict__ out_b,
    const float* __restrict__ Dp, const short* __restrict__ xln1b,
    const float* __restrict__ a_ssm, const float* __restrict__ g2,
    const float* __restrict__ bb2,
    float* __restrict__ xr, short* __restrict__ xn2) {
  __shared__ __align__(16) float smemf[64 * 193];  // 49.4 KB, aliased
  short* As = (short*)smemf;            // [192][72] bf16
  short* Bs = (short*)smemf + 192 * 72; // [64][72] bf16
  float* tile = smemf;                  // [64][193] f32 (post-MFMA)
  int l0g = blockIdx.x * 64, tid = threadIdx.x;
  int lane = tid & 63, l16 = lane & 15, quad = lane >> 4, wv = tid >> 6;
  for (int i = tid; i < 1536; i += 256) {
    int row = i >> 3, c8 = (i & 7) * 8;
    *(float4*)&As[row * 72 + c8] = *(const float4*)&owb[row * 64 + c8];
  }
  int bb = l0g >> 12, c0 = (l0g & 4095) >> 5;
  float xrv[3][4][4];
#pragma unroll
  for (int mi = 0; mi < 3; mi++)
#pragma unroll
    for (int r = 0; r < 4; r++) {
      int d = wv * 48 + mi * 16 + quad * 4 + r;
#pragma unroll
      for (int ni = 0; ni < 4; ni++) {
        int l = l0g + ni * 16 + l16;
        xrv[mi][r][ni] = xr[((size_t)bb * Dm + d) * Ln + (l & 4095)];
      }
    }
  if (wv < 2) {
    int c = c0 + wv, s = lane;
    float h = carries[(bb * 128 + c) * 64 + s];
    const float* ap = aA + (size_t)(l0g + wv * 32) * 64;
    const unsigned* bp = bxc + (size_t)(l0g + wv * 32) * 64;
    int t = 0;
    if (c == 0) {
      unsigned u = bp[s];
      h = b2f((short)(u & 0xFFFF));
      Bs[(wv * 32) * 72 + s] = f2b(b2f((short)(u >> 16)) * h);
      t = 1;
    }
#pragma unroll 4
    for (; t < 32; t++) {
      unsigned u = bp[t * 64 + s];
      float a = ap[t * 64 + s];
      h = a * (h + b2f((short)(u & 0xFFFF)));
      Bs[(wv * 32 + t) * 72 + s] = f2b(b2f((short)(u >> 16)) * h);
    }
  }
  __syncthreads();
  f32x4 acc[3][4] = {};
#pragma unroll
  for (int ks = 0; ks < 2; ks++) {
    int ko = ks * 32 + quad * 8;
    bf16x8 a[3], b[4];
#pragma unroll
    for (int mi = 0; mi < 3; mi++) a[mi] = *(const bf16x8*)&As[(wv * 48 + mi * 16 + l16) * 72 + ko];
#pragma unroll
    for (int ni = 0; ni < 4; ni++) b[ni] = *(const bf16x8*)&Bs[(ni * 16 + l16) * 72 + ko];
#pragma unroll
    for (int mi = 0; mi < 3; mi++)
#pragma unroll
      for (int ni = 0; ni < 4; ni++)
        acc[mi][ni] = __builtin_amdgcn_mfma_f32_16x16x32_bf16(a[mi], b[ni], acc[mi][ni], 0, 0, 0);
  }
  __syncthreads();
  float as_ = a_ssm[0];
#pragma unroll
  for (int mi = 0; mi < 3; mi++)
#pragma unroll
    for (int r = 0; r < 4; r++) {
      int d = wv * 48 + mi * 16 + quad * 4 + r;
      float ob = out_b[d];
      float dc = fminf(fmaxf(Dp[d], -2.f), 2.f);
#pragma unroll
      for (int ni = 0; ni < 4; ni++) {
        int l = l0g + ni * 16 + l16;
        float v = acc[mi][ni][r] + ob;
        if (dc != 0.f) v += dc * b2f(xln1b[(size_t)l * 192 + d]);
        size_t idx = ((size_t)bb * Dm + d) * Ln + (l & 4095);
        float nx = xrv[mi][r][ni] + as_ * v;
        xr[idx] = nx;
        tile[(l & 63) * 193 + d] = nx;
      }
    }
  __syncthreads();
  float g0 = g2[lane], g1v = g2[lane + 64], g2v = g2[lane + 128];
  float b0 = bb2[lane], b1v = bb2[lane + 64], b2v = bb2[lane + 128];
  for (int li = wv; li < 64; li += 4) {
    float v0 = tile[li * 193 + lane], v1 = tile[li * 193 + lane + 64], v2 = tile[li * 193 + lane + 128];
    float s  = wave_sum(v0 + v1 + v2);
    float sq = wave_sum(v0 * v0 + v1 * v1 + v2 * v2);
    float m = s * (1.f / 192.f);
    float inv = rsqrtf(sq * (1.f / 192.f) - m * m + 1e-5f);
    size_t base = (size_t)(l0g + li) * Dm;
    xn2[base + lane]       = f2b((v0 - m) * inv * g0 + b0);
    xn2[base + lane + 64]  = f2b((v1 - m) * inv * g1v + b1v);
    xn2[base + lane + 128] = f2b((v2 - m) * inv * g2v + b2v);
  }
}

// ---- K5: MFMA GEMM1: hid = gelu(xn2 @ w1^T + b1); grid (6,256) n-major -----
__global__ __launch_bounds__(256) void k_gemm1(
    const short* __restrict__ xn2, const short* __restrict__ w1b,
    const float* __restrict__ b1h, short* __restrict__ hid) {
  __shared__ __align__(16) short smem[2 * 128 * 88];
  short* As = smem;
  short* Bs = smem + 128 * 88;
  int m0 = blockIdx.y * 128, n0 = blockIdx.x * 128, tid = threadIdx.x;
  int lane = tid & 63, l16 = lane & 15, quad = lane >> 4;
  int wm = (tid >> 6) >> 1, wn = (tid >> 6) & 1;
  f32x4 acc[4][4] = {};
  for (int kt = 0; kt < 3; kt++) {
    int kb = kt * 64;
    for (int i = tid; i < 1024; i += 256) {
      int row = i >> 3, c8 = (i & 7) * 8;
      *(float4*)&As[row * 88 + c8] = *(const float4*)&xn2[(size_t)(m0 + row) * 192 + kb + c8];
      *(float4*)&Bs[row * 88 + c8] = *(const float4*)&w1b[(size_t)(n0 + row) * 192 + kb + c8];
    }
    __syncthreads();
#pragma unroll
    for (int ks = 0; ks < 2; ks++) {
      int ko = ks * 32 + quad * 8;
      bf16x8 a[4], b[4];
#pragma unroll
      for (int mi = 0; mi < 4; mi++) a[mi] = *(const bf16x8*)&As[(wm * 64 + mi * 16 + l16) * 88 + ko];
#pragma unroll
      for (int ni = 0; ni < 4; ni++) b[ni] = *(const bf16x8*)&Bs[(wn * 64 + ni * 16 + l16) * 88 + ko];
#pragma unroll
      for (int mi = 0; mi < 4; mi++)
#pragma unroll
        for (int ni = 0; ni < 4; ni++)
          acc[mi][ni] = __builtin_amdgcn_mfma_f32_16x16x32_bf16(a[mi], b[ni], acc[mi][ni], 0, 0, 0);
    }
    __syncthreads();
  }
  short* Cs = smem;
  float bias4[4];
#pragma unroll
  for (int ni = 0; ni < 4; ni++) bias4[ni] = b1h[n0 + wn * 64 + ni * 16 + l16];
#pragma unroll
  for (int mi = 0; mi < 4; mi++)
#pragma unroll
    for (int ni = 0; ni < 4; ni++) {
      int n = wn * 64 + ni * 16 + l16;
#pragma unroll
      for (int r = 0; r < 4; r++) {
        int m = wm * 64 + mi * 16 + quad * 4 + r;
        float v = acc[mi][ni][r] + bias4[ni];
        float g = 0.5f * v * (1.f + erff(v * 0.70710678118f));
        Cs[m * 136 + n] = f2b(g);
      }
    }
  __syncthreads();
  for (int i = tid; i < 2048; i += 256) {
    int m = i >> 4, ch = i & 15;
    *(float4*)&hid[(size_t)(m0 + m) * 768 + n0 + ch * 8] = *(const float4*)&Cs[m * 136 + ch * 8];
  }
}

// ---- K6: MFMA GEMM2 full-192-d (swapped, LDS staged): grid (512) ----------
__global__ __launch_bounds__(256) void k_gemm2(
    const short* __restrict__ hid, const short* __restrict__ w2b,
    const float* __restrict__ b2o, const float* __restrict__ xr,
    const float* __restrict__ am, float* __restrict__ out) {
  __shared__ __align__(16) short Wt[192 * 72];
  __shared__ __align__(16) short Ht[64 * 72];
  int l0g = blockIdx.x * 64, tid = threadIdx.x;
  int lane = tid & 63, l16 = lane & 15, quad = lane >> 4, wv = tid >> 6;
  f32x4 acc[3][4] = {};
  for (int kt = 0; kt < 12; kt++) {
    int kb = kt * 64;
    for (int i = tid; i < 1536; i += 256) {
      int row = i >> 3, c8 = (i & 7) * 8;
      *(float4*)&Wt[row * 72 + c8] = *(const float4*)&w2b[(size_t)row * 768 + kb + c8];
    }
    for (int i = tid; i < 512; i += 256) {
      int row = i >> 3, c8 = (i & 7) * 8;
      *(float4*)&Ht[row * 72 + c8] = *(const float4*)&hid[(size_t)(l0g + row) * 768 + kb + c8];
    }
    __syncthreads();
#pragma unroll
    for (int ks = 0; ks < 2; ks++) {
      int ko = ks * 32 + quad * 8;
      bf16x8 a[3], b[4];
#pragma unroll
      for (int mi = 0; mi < 3; mi++) a[mi] = *(const bf16x8*)&Wt[(wv * 48 + mi * 16 + l16) * 72 + ko];
#pragma unroll
      for (int ni = 0; ni < 4; ni++) b[ni] = *(const bf16x8*)&Ht[(ni * 16 + l16) * 72 + ko];
#pragma unroll
      for (int mi = 0; mi < 3; mi++)
#pragma unroll
        for (int ni = 0; ni < 4; ni++)
          acc[mi][ni] = __builtin_amdgcn_mfma_f32_16x16x32_bf16(a[mi], b[ni], acc[mi][ni], 0, 0, 0);
    }
    __syncthreads();
  }
  float alpha = am[0];
  int bb = l0g >> 12;
#pragma unroll
  for (int mi = 0; mi < 3; mi++)
#pragma unroll
    for (int r = 0; r < 4; r++) {
      int d = wv * 48 + mi * 16 + quad * 4 + r;
      float bias = b2o[d];
#pragma unroll
      for (int ni = 0; ni < 4; ni++) {
        int lg = l0g + ni * 16 + l16;
        size_t idx = ((size_t)bb * Dm + d) * Ln + (lg & 4095);
        out[idx] = xr[idx] + alpha * (acc[mi][ni][r] + bias);
      }
    }
}

extern "C" void kernel_launch(void* const* d_in, const int* in_sizes, int n_in,
                              void* d_out, int out_size, void* d_ws, size_t ws_size,
                              hipStream_t stream) {
  (void)in_sizes; (void)n_in; (void)out_size; (void)ws_size;
  const float* x     = (const float*)d_in[0];
  const float* ln1_g = (const float*)d_in[1];
  const float* ln1_b = (const float*)d_in[2];
  const float* ln2_g = (const float*)d_in[3];
  const float* ln2_b = (const float*)d_in[4];
  const float* dw_w  = (const float*)d_in[5];
  const float* bn_g  = (const float*)d_in[6];
  const float* bn_b  = (const float*)d_in[7];
  const float* bn_rm = (const float*)d_in[8];
  const float* bn_rv = (const float*)d_in[9];
  const float* ssm_g = (const float*)d_in[10];
  const float* ssm_b = (const float*)d_in[11];
  const float* xp_w  = (const float*)d_in[12];
  const float* xp_b  = (const float*)d_in[13];
  const float* dt_w  = (const float*)d_in[14];
  const float* dt_b  = (const float*)d_in[15];
  const float* A_log = (const float*)d_in[16];
  const float* B_w   = (const float*)d_in[17];
  const float* C_w   = (const float*)d_in[18];
  const float* Dp    = (const float*)d_in[19];
  const float* out_w = (const float*)d_in[20];
  const float* out_b = (const float*)d_in[21];
  const float* w1    = (const float*)d_in[22];
  const float* b1    = (const float*)d_in[23];
  const float* w2    = (const float*)d_in[24];
  const float* b2    = (const float*)d_in[25];
  const float* a_loc = (const float*)d_in[26];
  const float* a_ssm = (const float*)d_in[27];
  const float* a_mlp = (const float*)d_in[28];

  float* ws = (float*)d_ws;
  short*    xnb   = (short*)ws;                    // [32768,192] bf16
  short*    xln1b = (short*)(ws + 3145728);        // [32768,192] bf16
  float*    aA    = ws + 6291456;                  // [32768,64] f32
  unsigned* bxc   = (unsigned*)(ws + 8388608);     // [32768,64] packed bf16x2
  float*    xr    = ws + 17825792;                 // [8,192,4096] f32
  short*    wb    = (short*)(ws + 24117248);       // bf16 weights
  float*    sums  = ws + 24829952;                 // 131072 f
  float*    carr  = ws + 24961024;                 // 65536 f
  short*    xn2   = (short*)(ws + 25026560);       // [32768,192] bf16
  short*    hid   = (short*)(ws + 28172288);       // [32768,768] bf16
  short*    wcatb = wb;            // [256,192] = dt|B|C|xp rows
  short*    owb   = wb + 49152;    // [192,64]
  short*    w1b   = wb + 61440;    // [768,192]
  short*    w2b   = wb + 208896;   // [192,768]
  float*    out   = (float*)d_out;

  k_prep <<<dim3(64, 9),  256, 0, stream>>>(x, ln1_g, ln1_b, ssm_g, ssm_b, xnb, xln1b,
                                            dt_w, B_w, C_w, xp_w, out_w, w1, w2, wb);
  k_proj <<<dim3(512),    256, 0, stream>>>(xnb, wcatb, dt_b, xp_b, A_log, aA, bxc, sums);
  k_conv <<<dim3(193, 8), 256, 0, stream>>>(x, dw_w, bn_g, bn_b, bn_rm, bn_rv, a_loc, xr,
                                            sums, carr);
  k_out  <<<dim3(512),    256, 0, stream>>>(aA, bxc, carr, owb, out_b, Dp, xln1b,
                                            a_ssm, ln2_g, ln2_b, xr, xn2);
  k_gemm1<<<dim3(6, 256), 256, 0, stream>>>(xn2, w1b, b1, hid);
  k_gemm2<<<dim3(512),    256, 0, stream>>>(hid, w2b, b2, xr, a_mlp, out);
}

// Round 6
// 265.754 us; speedup vs baseline: 1.0288x; 1.0288x over previous
//
#include <hip/hip_runtime.h>
#include <hip/hip_bf16.h>
#include <math.h>

// MambaBlock v14: v13 with gemm2 fixed.
//  - k_gemm2 back to v12's split-d (96-d per block, 4 blocks/CU) but grid
//    swapped to (2,512): the two d-halves of one l-tile are dispatch-adjacent
//    -> Ht (hid rows) shared via L2, hid HBM fetch halved without the
//    occupancy loss that sank v13's full-192-d variant (44µs, 7% MfmaUtil).
//  - keeps v13's gemm1 (6,256) L2 grouping and conv+scan2 merge.
// Dispatches: 6.

#define DEV static __device__ __forceinline__

constexpr int Bn = 8, Dm = 192, Ln = 4096, Sn = 64, Hd = 768;

typedef __attribute__((ext_vector_type(8))) short bf16x8;
typedef __attribute__((ext_vector_type(4))) float f32x4;

DEV float wave_sum(float v) {
#pragma unroll
  for (int off = 1; off < 64; off <<= 1) v += __shfl_xor(v, off);
  return v;
}

DEV short f2b(float x) {
  __hip_bfloat16 h = __float2bfloat16(x);
  return *(short*)&h;
}

DEV float b2f(short x) {
  __hip_bfloat16 h = *(__hip_bfloat16*)&x;
  return __bfloat162float(h);
}

// ---- K1: prep = transpose+ln1+ssm_ln (y<8) fused with weight->bf16 (y==8) --
__global__ __launch_bounds__(256) void k_prep(
    const float* __restrict__ x, const float* __restrict__ g1, const float* __restrict__ b1,
    const float* __restrict__ g2, const float* __restrict__ b2,
    short* __restrict__ xnb, short* __restrict__ xln1b,
    const float* __restrict__ dt_w, const float* __restrict__ B_w,
    const float* __restrict__ C_w, const float* __restrict__ xp_w,
    const float* __restrict__ out_w, const float* __restrict__ w1,
    const float* __restrict__ w2, short* __restrict__ wb) {
  __shared__ __align__(16) float tile[Dm * 65];
  int tid = threadIdx.x;
  if (blockIdx.y == 8) {
    for (int i = blockIdx.x * 256 + tid; i < 89088; i += 64 * 256) {
      const float4* src;
      if (i < 3072)       src = (const float4*)dt_w + i;
      else if (i < 6144)  src = (const float4*)B_w + (i - 3072);
      else if (i < 9216)  src = (const float4*)C_w + (i - 6144);
      else if (i < 12288) src = (const float4*)xp_w + (i - 9216);
      else if (i < 15360) src = (const float4*)out_w + (i - 12288);
      else if (i < 52224) src = (const float4*)w1 + (i - 15360);
      else                src = (const float4*)w2 + (i - 52224);
      float4 v = *src;
      int o = i * 4;
      wb[o] = f2b(v.x); wb[o + 1] = f2b(v.y); wb[o + 2] = f2b(v.z); wb[o + 3] = f2b(v.w);
    }
    return;
  }
  int b = blockIdx.y, l0 = blockIdx.x * 64;
  const float* xb = x + (size_t)b * Dm * Ln;
  for (int i = tid; i < Dm * 16; i += 256) {
    int d = i >> 4, l4 = (i & 15) << 2;
    float4 v = *(const float4*)&xb[d * Ln + l0 + l4];
    tile[d * 65 + l4]     = v.x; tile[d * 65 + l4 + 1] = v.y;
    tile[d * 65 + l4 + 2] = v.z; tile[d * 65 + l4 + 3] = v.w;
  }
  __syncthreads();
  int lane = tid & 63, wv = tid >> 6;
  float ga0 = g1[lane], ga1 = g1[lane + 64], ga2 = g1[lane + 128];
  float bb0 = b1[lane], bb1 = b1[lane + 64], bb2 = b1[lane + 128];
  float gc0 = g2[lane], gc1 = g2[lane + 64], gc2 = g2[lane + 128];
  float bc0 = b2[lane], bc1 = b2[lane + 64], bc2 = b2[lane + 128];
  for (int li = wv; li < 64; li += 4) {
    float v0 = tile[lane * 65 + li], v1 = tile[(lane + 64) * 65 + li], v2 = tile[(lane + 128) * 65 + li];
    float s  = wave_sum(v0 + v1 + v2);
    float sq = wave_sum(v0 * v0 + v1 * v1 + v2 * v2);
    float m = s * (1.f / 192.f);
    float inv = rsqrtf(sq * (1.f / 192.f) - m * m + 1e-5f);
    float y0 = (v0 - m) * inv * ga0 + bb0;
    float y1 = (v1 - m) * inv * ga1 + bb1;
    float y2 = (v2 - m) * inv * ga2 + bb2;
    float s2  = wave_sum(y0 + y1 + y2);
    float sq2 = wave_sum(y0 * y0 + y1 * y1 + y2 * y2);
    float m2 = s2 * (1.f / 192.f);
    float inv2 = rsqrtf(sq2 * (1.f / 192.f) - m2 * m2 + 1e-5f);
    size_t base = ((size_t)b * Ln + l0 + li) * Dm;
    xln1b[base + lane]       = f2b(y0);
    xln1b[base + lane + 64]  = f2b(y1);
    xln1b[base + lane + 128] = f2b(y2);
    xnb[base + lane]       = f2b((y0 - m2) * inv2 * gc0 + bc0);
    xnb[base + lane + 64]  = f2b((y1 - m2) * inv2 * gc1 + bc1);
    xnb[base + lane + 128] = f2b((y2 - m2) * inv2 * gc2 + bc2);
  }
}

// ---- K2: MFMA proj GEMM + packed SSM epilogue + fused scan phase 1 ---------
__global__ __launch_bounds__(256) void k_proj(
    const short* __restrict__ xnb, const short* __restrict__ wcat,
    const float* __restrict__ dt_b, const float* __restrict__ xp_b,
    const float* __restrict__ A_log, float* __restrict__ aA, unsigned* __restrict__ bxc,
    float* __restrict__ sums) {
  __shared__ __align__(16) short As[64 * 72];
  __shared__ __align__(16) short Bs[256 * 72];
  int m0 = blockIdx.x * 64, tid = threadIdx.x;
  int lane = tid & 63, l16 = lane & 15, quad = lane >> 4, w = tid >> 6;
  f32x4 acc[16] = {};
  for (int kt = 0; kt < 3; kt++) {
    int kb = kt * 64;
    for (int i = tid; i < 512; i += 256) {
      int row = i >> 3, c8 = (i & 7) * 8;
      *(float4*)&As[row * 72 + c8] = *(const float4*)&xnb[(size_t)(m0 + row) * 192 + kb + c8];
    }
    for (int i = tid; i < 2048; i += 256) {
      int row = i >> 3, c8 = (i & 7) * 8;
      *(float4*)&Bs[row * 72 + c8] = *(const float4*)&wcat[(size_t)row * 192 + kb + c8];
    }
    __syncthreads();
#pragma unroll
    for (int ks = 0; ks < 2; ks++) {
      int ko = ks * 32 + quad * 8;
      bf16x8 a0 = *(const bf16x8*)&As[(w * 16 + l16) * 72 + ko];
#pragma unroll
      for (int nh = 0; nh < 2; nh++) {
        bf16x8 bfr[8];
#pragma unroll
        for (int j = 0; j < 8; j++) bfr[j] = *(const bf16x8*)&Bs[((nh * 8 + j) * 16 + l16) * 72 + ko];
#pragma unroll
        for (int j = 0; j < 8; j++)
          acc[nh * 8 + j] = __builtin_amdgcn_mfma_f32_16x16x32_bf16(a0, bfr[j], acc[nh * 8 + j], 0, 0, 0);
      }
    }
    __syncthreads();
  }
  float* aAs = (float*)Bs;        // [64][65] f32
  float* bxs = aAs + 64 * 65;     // [64][65] f32
  float Av[4], dtbv[4], xpbv[4];
#pragma unroll
  for (int ni = 0; ni < 4; ni++) {
    int s = ni * 16 + l16;
    Av[ni] = -expf(A_log[s]); dtbv[ni] = dt_b[s]; xpbv[ni] = xp_b[s];
  }
#pragma unroll
  for (int r = 0; r < 4; r++) {
    int lm = w * 16 + quad * 4 + r;
    int m = m0 + lm;
#pragma unroll
    for (int ni = 0; ni < 4; ni++) {
      int s = ni * 16 + l16;
      float z = acc[ni][r] + dtbv[ni];
      float sp = (z > 20.f) ? z : log1pf(expf(z));
      float delta = sp * 0.01f + 0.0001f;
      float bt  = acc[ni + 4][r];
      float ct  = acc[ni + 8][r];
      float xpv = acc[ni + 12][r] + xpbv[ni];
      float dA = fminf(fmaxf(delta * Av[ni], -10.f), -0.0001f);
      float Ae = fminf(fmaxf(expf(dA), 0.001f), 0.999f) + 1e-10f;
      short bxh = f2b(delta * bt * xpv);
      aA[(size_t)m * 64 + s] = Ae;
      unsigned pk = (unsigned)(unsigned short)bxh
                  | ((unsigned)(unsigned short)f2b(ct) << 16);
      bxc[(size_t)m * 64 + s] = pk;
      aAs[lm * 65 + s] = Ae;
      bxs[lm * 65 + s] = b2f(bxh);
    }
  }
  __syncthreads();
  int s = tid & 63, seg = tid >> 6, chunk = seg >> 1, sub = seg & 1;
  bool first = ((m0 & 4095) == 0) && (chunk == 0) && (sub == 0);
  float P = 1.f, H = 0.f;
  int base = chunk * 32 + sub * 16;
#pragma unroll
  for (int j = 0; j < 16; j++) {
    float a  = aAs[(base + j) * 65 + s];
    float bx = bxs[(base + j) * 65 + s];
    if (first && j == 0) { P = a; H = bx; }
    else { P *= a; H = a * (H + bx); }
  }
  float* partP = (float*)As;
  float* partH = partP + 256;
  partP[seg * 64 + s] = P; partH[seg * 64 + s] = H;
  __syncthreads();
  if (tid < 128) {
    int c = tid >> 6;
    float p0 = partP[(c * 2) * 64 + s], p1 = partP[(c * 2 + 1) * 64 + s];
    float h0 = partH[(c * 2) * 64 + s], h1 = partH[(c * 2 + 1) * 64 + s];
    int ci = (m0 >> 12) * 128 + ((m0 & 4095) >> 5) + c;
    sums[(ci * 2 + 0) * 64 + s] = p0 * p1;
    sums[(ci * 2 + 1) * 64 + s] = p1 * h0 + h1;
  }
}

// ---- K3: conv (x<192) + scan phase 2 (x==192) merged ----------------------
__global__ __launch_bounds__(256) void k_conv(
    const float* __restrict__ x, const float* __restrict__ dw,
    const float* __restrict__ bn_g, const float* __restrict__ bn_b,
    const float* __restrict__ bn_rm, const float* __restrict__ bn_rv,
    const float* __restrict__ a_loc, float* __restrict__ xr,
    const float* __restrict__ sums, float* __restrict__ carries) {
  __shared__ __align__(16) float xs[64 * 64];
  int tid = threadIdx.x;
  if (blockIdx.x == 192) {
    float* Pp = xs;            // [4][64]
    float* Hp = xs + 256;      // [4][64]
    int b = blockIdx.y, s = tid & 63, q = tid >> 6;
    float P = 1.f, H = 0.f;
#pragma unroll 4
    for (int j = 0; j < 32; j++) {
      int ci = b * 128 + q * 32 + j;
      float a = sums[(ci * 2 + 0) * 64 + s];
      float h = sums[(ci * 2 + 1) * 64 + s];
      P *= a; H = a * H + h;
    }
    Pp[q * 64 + s] = P; Hp[q * 64 + s] = H;
    __syncthreads();
    float cur = 0.f;
    for (int qq = 0; qq < q; qq++) cur = Pp[qq * 64 + s] * cur + Hp[qq * 64 + s];
#pragma unroll 4
    for (int j = 0; j < 32; j++) {
      int ci = b * 128 + q * 32 + j;
      carries[ci * 64 + s] = cur;
      float a = sums[(ci * 2 + 0) * 64 + s];
      float h = sums[(ci * 2 + 1) * 64 + s];
      cur = a * cur + h;
    }
    return;
  }
  int d = blockIdx.x, b = blockIdx.y;
  const float* xp = x + ((size_t)b * Dm + d) * Ln;
  for (int i = tid; i < 1024; i += 256) ((float4*)xs)[i] = ((const float4*)xp)[i];
  __syncthreads();
  float w[9];
#pragma unroll
  for (int k = 0; k < 9; k++) w[k] = dw[d * 9 + k];
  float scale = bn_g[d] * rsqrtf(bn_rv[d] + 1e-5f);
  float rm = bn_rm[d], bb = bn_b[d];
  float al = a_loc[0];
  float* xo = xr + ((size_t)b * Dm + d) * Ln;
  for (int i = tid; i < 4096; i += 256) {
    int h = i >> 6, wc = i & 63;
    float acc = 0.f;
#pragma unroll
    for (int kh = 0; kh < 3; kh++) {
      int hh = h + kh - 1;
      if (hh < 0 || hh >= 64) continue;
#pragma unroll
      for (int kw = 0; kw < 3; kw++) {
        int ww2 = wc + kw - 1;
        if (ww2 < 0 || ww2 >= 64) continue;
        acc += xs[hh * 64 + ww2] * w[kh * 3 + kw];
      }
    }
    float xl = (acc - rm) * scale + bb;
    xo[i] = xs[i] + al * xl;
  }
}

// ---- K4: fused scan replay + out-proj + combine (RMW xr) + LN2 -> xn2 ------
__global__ __launch_bounds__(256) void k_out(
    const float* __restrict__ aA, const unsigned* __restrict__ bxc,
    const float* __restrict__ carries,
    const short* __restrict__ owb, const float* __restrict__ out_b,
    const float* __restrict__ Dp, const short* __restrict__ xln1b,
    const float* __restrict__ a_ssm, const float* __restrict__ g2,
    const float* __restrict__ bb2,
    float* __restrict__ xr, short* __restrict__ xn2) {
  __shared__ __align__(16) float smemf[64 * 193];  // 49.4 KB, aliased
  short* As = (short*)smemf;            // [192][72] bf16
  short* Bs = (short*)smemf + 192 * 72; // [64][72] bf16
  float* tile = smemf;                  // [64][193] f32 (post-MFMA)
  int l0g = blockIdx.x * 64, tid = threadIdx.x;
  int lane = tid & 63, l16 = lane & 15, quad = lane >> 4, wv = tid >> 6;
  for (int i = tid; i < 1536; i += 256) {
    int row = i >> 3, c8 = (i & 7) * 8;
    *(float4*)&As[row * 72 + c8] = *(const float4*)&owb[row * 64 + c8];
  }
  int bb = l0g >> 12, c0 = (l0g & 4095) >> 5;
  float xrv[3][4][4];
#pragma unroll
  for (int mi = 0; mi < 3; mi++)
#pragma unroll
    for (int r = 0; r < 4; r++) {
      int d = wv * 48 + mi * 16 + quad * 4 + r;
#pragma unroll
      for (int ni = 0; ni < 4; ni++) {
        int l = l0g + ni * 16 + l16;
        xrv[mi][r][ni] = xr[((size_t)bb * Dm + d) * Ln + (l & 4095)];
      }
    }
  if (wv < 2) {
    int c = c0 + wv, s = lane;
    float h = carries[(bb * 128 + c) * 64 + s];
    const float* ap = aA + (size_t)(l0g + wv * 32) * 64;
    const unsigned* bp = bxc + (size_t)(l0g + wv * 32) * 64;
    int t = 0;
    if (c == 0) {
      unsigned u = bp[s];
      h = b2f((short)(u & 0xFFFF));
      Bs[(wv * 32) * 72 + s] = f2b(b2f((short)(u >> 16)) * h);
      t = 1;
    }
#pragma unroll 4
    for (; t < 32; t++) {
      unsigned u = bp[t * 64 + s];
      float a = ap[t * 64 + s];
      h = a * (h + b2f((short)(u & 0xFFFF)));
      Bs[(wv * 32 + t) * 72 + s] = f2b(b2f((short)(u >> 16)) * h);
    }
  }
  __syncthreads();
  f32x4 acc[3][4] = {};
#pragma unroll
  for (int ks = 0; ks < 2; ks++) {
    int ko = ks * 32 + quad * 8;
    bf16x8 a[3], b[4];
#pragma unroll
    for (int mi = 0; mi < 3; mi++) a[mi] = *(const bf16x8*)&As[(wv * 48 + mi * 16 + l16) * 72 + ko];
#pragma unroll
    for (int ni = 0; ni < 4; ni++) b[ni] = *(const bf16x8*)&Bs[(ni * 16 + l16) * 72 + ko];
#pragma unroll
    for (int mi = 0; mi < 3; mi++)
#pragma unroll
      for (int ni = 0; ni < 4; ni++)
        acc[mi][ni] = __builtin_amdgcn_mfma_f32_16x16x32_bf16(a[mi], b[ni], acc[mi][ni], 0, 0, 0);
  }
  __syncthreads();
  float as_ = a_ssm[0];
#pragma unroll
  for (int mi = 0; mi < 3; mi++)
#pragma unroll
    for (int r = 0; r < 4; r++) {
      int d = wv * 48 + mi * 16 + quad * 4 + r;
      float ob = out_b[d];
      float dc = fminf(fmaxf(Dp[d], -2.f), 2.f);
#pragma unroll
      for (int ni = 0; ni < 4; ni++) {
        int l = l0g + ni * 16 + l16;
        float v = acc[mi][ni][r] + ob;
        if (dc != 0.f) v += dc * b2f(xln1b[(size_t)l * 192 + d]);
        size_t idx = ((size_t)bb * Dm + d) * Ln + (l & 4095);
        float nx = xrv[mi][r][ni] + as_ * v;
        xr[idx] = nx;
        tile[(l & 63) * 193 + d] = nx;
      }
    }
  __syncthreads();
  float g0 = g2[lane], g1v = g2[lane + 64], g2v = g2[lane + 128];
  float b0 = bb2[lane], b1v = bb2[lane + 64], b2v = bb2[lane + 128];
  for (int li = wv; li < 64; li += 4) {
    float v0 = tile[li * 193 + lane], v1 = tile[li * 193 + lane + 64], v2 = tile[li * 193 + lane + 128];
    float s  = wave_sum(v0 + v1 + v2);
    float sq = wave_sum(v0 * v0 + v1 * v1 + v2 * v2);
    float m = s * (1.f / 192.f);
    float inv = rsqrtf(sq * (1.f / 192.f) - m * m + 1e-5f);
    size_t base = (size_t)(l0g + li) * Dm;
    xn2[base + lane]       = f2b((v0 - m) * inv * g0 + b0);
    xn2[base + lane + 64]  = f2b((v1 - m) * inv * g1v + b1v);
    xn2[base + lane + 128] = f2b((v2 - m) * inv * g2v + b2v);
  }
}

// ---- K5: MFMA GEMM1: hid = gelu(xn2 @ w1^T + b1); grid (6,256) n-major -----
__global__ __launch_bounds__(256) void k_gemm1(
    const short* __restrict__ xn2, const short* __restrict__ w1b,
    const float* __restrict__ b1h, short* __restrict__ hid) {
  __shared__ __align__(16) short smem[2 * 128 * 88];
  short* As = smem;
  short* Bs = smem + 128 * 88;
  int m0 = blockIdx.y * 128, n0 = blockIdx.x * 128, tid = threadIdx.x;
  int lane = tid & 63, l16 = lane & 15, quad = lane >> 4;
  int wm = (tid >> 6) >> 1, wn = (tid >> 6) & 1;
  f32x4 acc[4][4] = {};
  for (int kt = 0; kt < 3; kt++) {
    int kb = kt * 64;
    for (int i = tid; i < 1024; i += 256) {
      int row = i >> 3, c8 = (i & 7) * 8;
      *(float4*)&As[row * 88 + c8] = *(const float4*)&xn2[(size_t)(m0 + row) * 192 + kb + c8];
      *(float4*)&Bs[row * 88 + c8] = *(const float4*)&w1b[(size_t)(n0 + row) * 192 + kb + c8];
    }
    __syncthreads();
#pragma unroll
    for (int ks = 0; ks < 2; ks++) {
      int ko = ks * 32 + quad * 8;
      bf16x8 a[4], b[4];
#pragma unroll
      for (int mi = 0; mi < 4; mi++) a[mi] = *(const bf16x8*)&As[(wm * 64 + mi * 16 + l16) * 88 + ko];
#pragma unroll
      for (int ni = 0; ni < 4; ni++) b[ni] = *(const bf16x8*)&Bs[(wn * 64 + ni * 16 + l16) * 88 + ko];
#pragma unroll
      for (int mi = 0; mi < 4; mi++)
#pragma unroll
        for (int ni = 0; ni < 4; ni++)
          acc[mi][ni] = __builtin_amdgcn_mfma_f32_16x16x32_bf16(a[mi], b[ni], acc[mi][ni], 0, 0, 0);
    }
    __syncthreads();
  }
  short* Cs = smem;
  float bias4[4];
#pragma unroll
  for (int ni = 0; ni < 4; ni++) bias4[ni] = b1h[n0 + wn * 64 + ni * 16 + l16];
#pragma unroll
  for (int mi = 0; mi < 4; mi++)
#pragma unroll
    for (int ni = 0; ni < 4; ni++) {
      int n = wn * 64 + ni * 16 + l16;
#pragma unroll
      for (int r = 0; r < 4; r++) {
        int m = wm * 64 + mi * 16 + quad * 4 + r;
        float v = acc[mi][ni][r] + bias4[ni];
        float g = 0.5f * v * (1.f + erff(v * 0.70710678118f));
        Cs[m * 136 + n] = f2b(g);
      }
    }
  __syncthreads();
  for (int i = tid; i < 2048; i += 256) {
    int m = i >> 4, ch = i & 15;
    *(float4*)&hid[(size_t)(m0 + m) * 768 + n0 + ch * 8] = *(const float4*)&Cs[m * 136 + ch * 8];
  }
}

// ---- K6: MFMA GEMM2 (swapped, split-d, LDS staged): grid (2,512) ----------
// x = d-half, y = l-tile: the two d-halves reading the same Ht rows are
// dispatch-adjacent -> hid served once from HBM, second read hits L2.
__global__ __launch_bounds__(256) void k_gemm2(
    const short* __restrict__ hid, const short* __restrict__ w2b,
    const float* __restrict__ b2o, const float* __restrict__ xr,
    const float* __restrict__ am, float* __restrict__ out) {
  __shared__ __align__(16) short Wt[96 * 88];
  __shared__ __align__(16) short Ht[64 * 88];
  int l0g = blockIdx.y * 64, d0 = blockIdx.x * 96, tid = threadIdx.x;
  int lane = tid & 63, l16 = lane & 15, quad = lane >> 4;
  int wm = (tid >> 6) >> 1, wn = (tid >> 6) & 1;
  f32x4 acc[3][2] = {};
  for (int kt = 0; kt < 12; kt++) {
    int kb = kt * 64;
    for (int i = tid; i < 768; i += 256) {
      int row = i >> 3, c8 = (i & 7) * 8;
      *(float4*)&Wt[row * 88 + c8] = *(const float4*)&w2b[(size_t)(d0 + row) * 768 + kb + c8];
    }
    for (int i = tid; i < 512; i += 256) {
      int row = i >> 3, c8 = (i & 7) * 8;
      *(float4*)&Ht[row * 88 + c8] = *(const float4*)&hid[(size_t)(l0g + row) * 768 + kb + c8];
    }
    __syncthreads();
#pragma unroll
    for (int ks = 0; ks < 2; ks++) {
      int ko = ks * 32 + quad * 8;
      bf16x8 a[3], b[2];
#pragma unroll
      for (int mi = 0; mi < 3; mi++) a[mi] = *(const bf16x8*)&Wt[(wm * 48 + mi * 16 + l16) * 88 + ko];
#pragma unroll
      for (int ni = 0; ni < 2; ni++) b[ni] = *(const bf16x8*)&Ht[(wn * 32 + ni * 16 + l16) * 88 + ko];
#pragma unroll
      for (int mi = 0; mi < 3; mi++)
#pragma unroll
        for (int ni = 0; ni < 2; ni++)
          acc[mi][ni] = __builtin_amdgcn_mfma_f32_16x16x32_bf16(a[mi], b[ni], acc[mi][ni], 0, 0, 0);
    }
    __syncthreads();
  }
  float alpha = am[0];
#pragma unroll
  for (int mi = 0; mi < 3; mi++)
#pragma unroll
    for (int r = 0; r < 4; r++) {
      int d = d0 + wm * 48 + mi * 16 + quad * 4 + r;
      float bias = b2o[d];
#pragma unroll
      for (int ni = 0; ni < 2; ni++) {
        int lg = l0g + wn * 32 + ni * 16 + l16;
        size_t idx = ((size_t)(lg >> 12) * Dm + d) * Ln + (lg & 4095);
        out[idx] = xr[idx] + alpha * (acc[mi][ni][r] + bias);
      }
    }
}

extern "C" void kernel_launch(void* const* d_in, const int* in_sizes, int n_in,
                              void* d_out, int out_size, void* d_ws, size_t ws_size,
                              hipStream_t stream) {
  (void)in_sizes; (void)n_in; (void)out_size; (void)ws_size;
  const float* x     = (const float*)d_in[0];
  const float* ln1_g = (const float*)d_in[1];
  const float* ln1_b = (const float*)d_in[2];
  const float* ln2_g = (const float*)d_in[3];
  const float* ln2_b = (const float*)d_in[4];
  const float* dw_w  = (const float*)d_in[5];
  const float* bn_g  = (const float*)d_in[6];
  const float* bn_b  = (const float*)d_in[7];
  const float* bn_rm = (const float*)d_in[8];
  const float* bn_rv = (const float*)d_in[9];
  const float* ssm_g = (const float*)d_in[10];
  const float* ssm_b = (const float*)d_in[11];
  const float* xp_w  = (const float*)d_in[12];
  const float* xp_b  = (const float*)d_in[13];
  const float* dt_w  = (const float*)d_in[14];
  const float* dt_b  = (const float*)d_in[15];
  const float* A_log = (const float*)d_in[16];
  const float* B_w   = (const float*)d_in[17];
  const float* C_w   = (const float*)d_in[18];
  const float* Dp    = (const float*)d_in[19];
  const float* out_w = (const float*)d_in[20];
  const float* out_b = (const float*)d_in[21];
  const float* w1    = (const float*)d_in[22];
  const float* b1    = (const float*)d_in[23];
  const float* w2    = (const float*)d_in[24];
  const float* b2    = (const float*)d_in[25];
  const float* a_loc = (const float*)d_in[26];
  const float* a_ssm = (const float*)d_in[27];
  const float* a_mlp = (const float*)d_in[28];

  float* ws = (float*)d_ws;
  short*    xnb   = (short*)ws;                    // [32768,192] bf16
  short*    xln1b = (short*)(ws + 3145728);        // [32768,192] bf16
  float*    aA    = ws + 6291456;                  // [32768,64] f32
  unsigned* bxc   = (unsigned*)(ws + 8388608);     // [32768,64] packed bf16x2
  float*    xr    = ws + 17825792;                 // [8,192,4096] f32
  short*    wb    = (short*)(ws + 24117248);       // bf16 weights
  float*    sums  = ws + 24829952;                 // 131072 f
  float*    carr  = ws + 24961024;                 // 65536 f
  short*    xn2   = (short*)(ws + 25026560);       // [32768,192] bf16
  short*    hid   = (short*)(ws + 28172288);       // [32768,768] bf16
  short*    wcatb = wb;            // [256,192] = dt|B|C|xp rows
  short*    owb   = wb + 49152;    // [192,64]
  short*    w1b   = wb + 61440;    // [768,192]
  short*    w2b   = wb + 208896;   // [192,768]
  float*    out   = (float*)d_out;

  k_prep <<<dim3(64, 9),  256, 0, stream>>>(x, ln1_g, ln1_b, ssm_g, ssm_b, xnb, xln1b,
                                            dt_w, B_w, C_w, xp_w, out_w, w1, w2, wb);
  k_proj <<<dim3(512),    256, 0, stream>>>(xnb, wcatb, dt_b, xp_b, A_log, aA, bxc, sums);
  k_conv <<<dim3(193, 8), 256, 0, stream>>>(x, dw_w, bn_g, bn_b, bn_rm, bn_rv, a_loc, xr,
                                            sums, carr);
  k_out  <<<dim3(512),    256, 0, stream>>>(aA, bxc, carr, owb, out_b, Dp, xln1b,
                                            a_ssm, ln2_g, ln2_b, xr, xn2);
  k_gemm1<<<dim3(6, 256), 256, 0, stream>>>(xn2, w1b, b1, hid);
  k_gemm2<<<dim3(2, 512), 256, 0, stream>>>(hid, w2b, b2, xr, a_mlp, out);
}

// Round 7
// 261.173 us; speedup vs baseline: 1.0468x; 1.0175x over previous
//
#include <hip/hip_runtime.h>
#include <hip/hip_bf16.h>
#include <math.h>

// MambaBlock v15: v14 + XCD-aware block swizzle on both MLP GEMMs.
//  Root cause of gemm1's 70µs / 3x over-fetch: blocks sharing an xn2 A-tile
//  were dispatch-adjacent -> round-robined onto DIFFERENT XCDs (private L2s),
//  so each XCD refetched the tile from HBM. Fix: flat grid + in-kernel map
//  putting all sharers on one XCD (bid&7 = xcd, consecutive on it).
//  Also LDS stride 88->72 on both gemms (2-way bank alias = free): gemm1
//  45->36.9KB (4 blk/CU), gemm2 28->23KB (6 blk/CU).

#define DEV static __device__ __forceinline__

constexpr int Bn = 8, Dm = 192, Ln = 4096, Sn = 64, Hd = 768;

typedef __attribute__((ext_vector_type(8))) short bf16x8;
typedef __attribute__((ext_vector_type(4))) float f32x4;

DEV float wave_sum(float v) {
#pragma unroll
  for (int off = 1; off < 64; off <<= 1) v += __shfl_xor(v, off);
  return v;
}

DEV short f2b(float x) {
  __hip_bfloat16 h = __float2bfloat16(x);
  return *(short*)&h;
}

DEV float b2f(short x) {
  __hip_bfloat16 h = *(__hip_bfloat16*)&x;
  return __bfloat162float(h);
}

// ---- K1: prep = transpose+ln1+ssm_ln (y<8) fused with weight->bf16 (y==8) --
__global__ __launch_bounds__(256) void k_prep(
    const float* __restrict__ x, const float* __restrict__ g1, const float* __restrict__ b1,
    const float* __restrict__ g2, const float* __restrict__ b2,
    short* __restrict__ xnb, short* __restrict__ xln1b,
    const float* __restrict__ dt_w, const float* __restrict__ B_w,
    const float* __restrict__ C_w, const float* __restrict__ xp_w,
    const float* __restrict__ out_w, const float* __restrict__ w1,
    const float* __restrict__ w2, short* __restrict__ wb) {
  __shared__ __align__(16) float tile[Dm * 65];
  int tid = threadIdx.x;
  if (blockIdx.y == 8) {
    for (int i = blockIdx.x * 256 + tid; i < 89088; i += 64 * 256) {
      const float4* src;
      if (i < 3072)       src = (const float4*)dt_w + i;
      else if (i < 6144)  src = (const float4*)B_w + (i - 3072);
      else if (i < 9216)  src = (const float4*)C_w + (i - 6144);
      else if (i < 12288) src = (const float4*)xp_w + (i - 9216);
      else if (i < 15360) src = (const float4*)out_w + (i - 12288);
      else if (i < 52224) src = (const float4*)w1 + (i - 15360);
      else                src = (const float4*)w2 + (i - 52224);
      float4 v = *src;
      int o = i * 4;
      wb[o] = f2b(v.x); wb[o + 1] = f2b(v.y); wb[o + 2] = f2b(v.z); wb[o + 3] = f2b(v.w);
    }
    return;
  }
  int b = blockIdx.y, l0 = blockIdx.x * 64;
  const float* xb = x + (size_t)b * Dm * Ln;
  for (int i = tid; i < Dm * 16; i += 256) {
    int d = i >> 4, l4 = (i & 15) << 2;
    float4 v = *(const float4*)&xb[d * Ln + l0 + l4];
    tile[d * 65 + l4]     = v.x; tile[d * 65 + l4 + 1] = v.y;
    tile[d * 65 + l4 + 2] = v.z; tile[d * 65 + l4 + 3] = v.w;
  }
  __syncthreads();
  int lane = tid & 63, wv = tid >> 6;
  float ga0 = g1[lane], ga1 = g1[lane + 64], ga2 = g1[lane + 128];
  float bb0 = b1[lane], bb1 = b1[lane + 64], bb2 = b1[lane + 128];
  float gc0 = g2[lane], gc1 = g2[lane + 64], gc2 = g2[lane + 128];
  float bc0 = b2[lane], bc1 = b2[lane + 64], bc2 = b2[lane + 128];
  for (int li = wv; li < 64; li += 4) {
    float v0 = tile[lane * 65 + li], v1 = tile[(lane + 64) * 65 + li], v2 = tile[(lane + 128) * 65 + li];
    float s  = wave_sum(v0 + v1 + v2);
    float sq = wave_sum(v0 * v0 + v1 * v1 + v2 * v2);
    float m = s * (1.f / 192.f);
    float inv = rsqrtf(sq * (1.f / 192.f) - m * m + 1e-5f);
    float y0 = (v0 - m) * inv * ga0 + bb0;
    float y1 = (v1 - m) * inv * ga1 + bb1;
    float y2 = (v2 - m) * inv * ga2 + bb2;
    float s2  = wave_sum(y0 + y1 + y2);
    float sq2 = wave_sum(y0 * y0 + y1 * y1 + y2 * y2);
    float m2 = s2 * (1.f / 192.f);
    float inv2 = rsqrtf(sq2 * (1.f / 192.f) - m2 * m2 + 1e-5f);
    size_t base = ((size_t)b * Ln + l0 + li) * Dm;
    xln1b[base + lane]       = f2b(y0);
    xln1b[base + lane + 64]  = f2b(y1);
    xln1b[base + lane + 128] = f2b(y2);
    xnb[base + lane]       = f2b((y0 - m2) * inv2 * gc0 + bc0);
    xnb[base + lane + 64]  = f2b((y1 - m2) * inv2 * gc1 + bc1);
    xnb[base + lane + 128] = f2b((y2 - m2) * inv2 * gc2 + bc2);
  }
}

// ---- K2: MFMA proj GEMM + packed SSM epilogue + fused scan phase 1 ---------
__global__ __launch_bounds__(256) void k_proj(
    const short* __restrict__ xnb, const short* __restrict__ wcat,
    const float* __restrict__ dt_b, const float* __restrict__ xp_b,
    const float* __restrict__ A_log, float* __restrict__ aA, unsigned* __restrict__ bxc,
    float* __restrict__ sums) {
  __shared__ __align__(16) short As[64 * 72];
  __shared__ __align__(16) short Bs[256 * 72];
  int m0 = blockIdx.x * 64, tid = threadIdx.x;
  int lane = tid & 63, l16 = lane & 15, quad = lane >> 4, w = tid >> 6;
  f32x4 acc[16] = {};
  for (int kt = 0; kt < 3; kt++) {
    int kb = kt * 64;
    for (int i = tid; i < 512; i += 256) {
      int row = i >> 3, c8 = (i & 7) * 8;
      *(float4*)&As[row * 72 + c8] = *(const float4*)&xnb[(size_t)(m0 + row) * 192 + kb + c8];
    }
    for (int i = tid; i < 2048; i += 256) {
      int row = i >> 3, c8 = (i & 7) * 8;
      *(float4*)&Bs[row * 72 + c8] = *(const float4*)&wcat[(size_t)row * 192 + kb + c8];
    }
    __syncthreads();
#pragma unroll
    for (int ks = 0; ks < 2; ks++) {
      int ko = ks * 32 + quad * 8;
      bf16x8 a0 = *(const bf16x8*)&As[(w * 16 + l16) * 72 + ko];
#pragma unroll
      for (int nh = 0; nh < 2; nh++) {
        bf16x8 bfr[8];
#pragma unroll
        for (int j = 0; j < 8; j++) bfr[j] = *(const bf16x8*)&Bs[((nh * 8 + j) * 16 + l16) * 72 + ko];
#pragma unroll
        for (int j = 0; j < 8; j++)
          acc[nh * 8 + j] = __builtin_amdgcn_mfma_f32_16x16x32_bf16(a0, bfr[j], acc[nh * 8 + j], 0, 0, 0);
      }
    }
    __syncthreads();
  }
  float* aAs = (float*)Bs;        // [64][65] f32
  float* bxs = aAs + 64 * 65;     // [64][65] f32
  float Av[4], dtbv[4], xpbv[4];
#pragma unroll
  for (int ni = 0; ni < 4; ni++) {
    int s = ni * 16 + l16;
    Av[ni] = -expf(A_log[s]); dtbv[ni] = dt_b[s]; xpbv[ni] = xp_b[s];
  }
#pragma unroll
  for (int r = 0; r < 4; r++) {
    int lm = w * 16 + quad * 4 + r;
    int m = m0 + lm;
#pragma unroll
    for (int ni = 0; ni < 4; ni++) {
      int s = ni * 16 + l16;
      float z = acc[ni][r] + dtbv[ni];
      float sp = (z > 20.f) ? z : log1pf(expf(z));
      float delta = sp * 0.01f + 0.0001f;
      float bt  = acc[ni + 4][r];
      float ct  = acc[ni + 8][r];
      float xpv = acc[ni + 12][r] + xpbv[ni];
      float dA = fminf(fmaxf(delta * Av[ni], -10.f), -0.0001f);
      float Ae = fminf(fmaxf(expf(dA), 0.001f), 0.999f) + 1e-10f;
      short bxh = f2b(delta * bt * xpv);
      aA[(size_t)m * 64 + s] = Ae;
      unsigned pk = (unsigned)(unsigned short)bxh
                  | ((unsigned)(unsigned short)f2b(ct) << 16);
      bxc[(size_t)m * 64 + s] = pk;
      aAs[lm * 65 + s] = Ae;
      bxs[lm * 65 + s] = b2f(bxh);
    }
  }
  __syncthreads();
  int s = tid & 63, seg = tid >> 6, chunk = seg >> 1, sub = seg & 1;
  bool first = ((m0 & 4095) == 0) && (chunk == 0) && (sub == 0);
  float P = 1.f, H = 0.f;
  int base = chunk * 32 + sub * 16;
#pragma unroll
  for (int j = 0; j < 16; j++) {
    float a  = aAs[(base + j) * 65 + s];
    float bx = bxs[(base + j) * 65 + s];
    if (first && j == 0) { P = a; H = bx; }
    else { P *= a; H = a * (H + bx); }
  }
  float* partP = (float*)As;
  float* partH = partP + 256;
  partP[seg * 64 + s] = P; partH[seg * 64 + s] = H;
  __syncthreads();
  if (tid < 128) {
    int c = tid >> 6;
    float p0 = partP[(c * 2) * 64 + s], p1 = partP[(c * 2 + 1) * 64 + s];
    float h0 = partH[(c * 2) * 64 + s], h1 = partH[(c * 2 + 1) * 64 + s];
    int ci = (m0 >> 12) * 128 + ((m0 & 4095) >> 5) + c;
    sums[(ci * 2 + 0) * 64 + s] = p0 * p1;
    sums[(ci * 2 + 1) * 64 + s] = p1 * h0 + h1;
  }
}

// ---- K3: conv (x<192) + scan phase 2 (x==192) merged ----------------------
__global__ __launch_bounds__(256) void k_conv(
    const float* __restrict__ x, const float* __restrict__ dw,
    const float* __restrict__ bn_g, const float* __restrict__ bn_b,
    const float* __restrict__ bn_rm, const float* __restrict__ bn_rv,
    const float* __restrict__ a_loc, float* __restrict__ xr,
    const float* __restrict__ sums, float* __restrict__ carries) {
  __shared__ __align__(16) float xs[64 * 64];
  int tid = threadIdx.x;
  if (blockIdx.x == 192) {
    float* Pp = xs;            // [4][64]
    float* Hp = xs + 256;      // [4][64]
    int b = blockIdx.y, s = tid & 63, q = tid >> 6;
    float P = 1.f, H = 0.f;
#pragma unroll 4
    for (int j = 0; j < 32; j++) {
      int ci = b * 128 + q * 32 + j;
      float a = sums[(ci * 2 + 0) * 64 + s];
      float h = sums[(ci * 2 + 1) * 64 + s];
      P *= a; H = a * H + h;
    }
    Pp[q * 64 + s] = P; Hp[q * 64 + s] = H;
    __syncthreads();
    float cur = 0.f;
    for (int qq = 0; qq < q; qq++) cur = Pp[qq * 64 + s] * cur + Hp[qq * 64 + s];
#pragma unroll 4
    for (int j = 0; j < 32; j++) {
      int ci = b * 128 + q * 32 + j;
      carries[ci * 64 + s] = cur;
      float a = sums[(ci * 2 + 0) * 64 + s];
      float h = sums[(ci * 2 + 1) * 64 + s];
      cur = a * cur + h;
    }
    return;
  }
  int d = blockIdx.x, b = blockIdx.y;
  const float* xp = x + ((size_t)b * Dm + d) * Ln;
  for (int i = tid; i < 1024; i += 256) ((float4*)xs)[i] = ((const float4*)xp)[i];
  __syncthreads();
  float w[9];
#pragma unroll
  for (int k = 0; k < 9; k++) w[k] = dw[d * 9 + k];
  float scale = bn_g[d] * rsqrtf(bn_rv[d] + 1e-5f);
  float rm = bn_rm[d], bb = bn_b[d];
  float al = a_loc[0];
  float* xo = xr + ((size_t)b * Dm + d) * Ln;
  for (int i = tid; i < 4096; i += 256) {
    int h = i >> 6, wc = i & 63;
    float acc = 0.f;
#pragma unroll
    for (int kh = 0; kh < 3; kh++) {
      int hh = h + kh - 1;
      if (hh < 0 || hh >= 64) continue;
#pragma unroll
      for (int kw = 0; kw < 3; kw++) {
        int ww2 = wc + kw - 1;
        if (ww2 < 0 || ww2 >= 64) continue;
        acc += xs[hh * 64 + ww2] * w[kh * 3 + kw];
      }
    }
    float xl = (acc - rm) * scale + bb;
    xo[i] = xs[i] + al * xl;
  }
}

// ---- K4: fused scan replay + out-proj + combine (RMW xr) + LN2 -> xn2 ------
__global__ __launch_bounds__(256) void k_out(
    const float* __restrict__ aA, const unsigned* __restrict__ bxc,
    const float* __restrict__ carries,
    const short* __restrict__ owb, const float* __restrict__ out_b,
    const float* __restrict__ Dp, const short* __restrict__ xln1b,
    const float* __restrict__ a_ssm, const float* __restrict__ g2,
    const float* __restrict__ bb2,
    float* __restrict__ xr, short* __restrict__ xn2) {
  __shared__ __align__(16) float smemf[64 * 193];  // 49.4 KB, aliased
  short* As = (short*)smemf;            // [192][72] bf16
  short* Bs = (short*)smemf + 192 * 72; // [64][72] bf16
  float* tile = smemf;                  // [64][193] f32 (post-MFMA)
  int l0g = blockIdx.x * 64, tid = threadIdx.x;
  int lane = tid & 63, l16 = lane & 15, quad = lane >> 4, wv = tid >> 6;
  for (int i = tid; i < 1536; i += 256) {
    int row = i >> 3, c8 = (i & 7) * 8;
    *(float4*)&As[row * 72 + c8] = *(const float4*)&owb[row * 64 + c8];
  }
  int bb = l0g >> 12, c0 = (l0g & 4095) >> 5;
  float xrv[3][4][4];
#pragma unroll
  for (int mi = 0; mi < 3; mi++)
#pragma unroll
    for (int r = 0; r < 4; r++) {
      int d = wv * 48 + mi * 16 + quad * 4 + r;
#pragma unroll
      for (int ni = 0; ni < 4; ni++) {
        int l = l0g + ni * 16 + l16;
        xrv[mi][r][ni] = xr[((size_t)bb * Dm + d) * Ln + (l & 4095)];
      }
    }
  if (wv < 2) {
    int c = c0 + wv, s = lane;
    float h = carries[(bb * 128 + c) * 64 + s];
    const float* ap = aA + (size_t)(l0g + wv * 32) * 64;
    const unsigned* bp = bxc + (size_t)(l0g + wv * 32) * 64;
    int t = 0;
    if (c == 0) {
      unsigned u = bp[s];
      h = b2f((short)(u & 0xFFFF));
      Bs[(wv * 32) * 72 + s] = f2b(b2f((short)(u >> 16)) * h);
      t = 1;
    }
#pragma unroll 4
    for (; t < 32; t++) {
      unsigned u = bp[t * 64 + s];
      float a = ap[t * 64 + s];
      h = a * (h + b2f((short)(u & 0xFFFF)));
      Bs[(wv * 32 + t) * 72 + s] = f2b(b2f((short)(u >> 16)) * h);
    }
  }
  __syncthreads();
  f32x4 acc[3][4] = {};
#pragma unroll
  for (int ks = 0; ks < 2; ks++) {
    int ko = ks * 32 + quad * 8;
    bf16x8 a[3], b[4];
#pragma unroll
    for (int mi = 0; mi < 3; mi++) a[mi] = *(const bf16x8*)&As[(wv * 48 + mi * 16 + l16) * 72 + ko];
#pragma unroll
    for (int ni = 0; ni < 4; ni++) b[ni] = *(const bf16x8*)&Bs[(ni * 16 + l16) * 72 + ko];
#pragma unroll
    for (int mi = 0; mi < 3; mi++)
#pragma unroll
      for (int ni = 0; ni < 4; ni++)
        acc[mi][ni] = __builtin_amdgcn_mfma_f32_16x16x32_bf16(a[mi], b[ni], acc[mi][ni], 0, 0, 0);
  }
  __syncthreads();
  float as_ = a_ssm[0];
#pragma unroll
  for (int mi = 0; mi < 3; mi++)
#pragma unroll
    for (int r = 0; r < 4; r++) {
      int d = wv * 48 + mi * 16 + quad * 4 + r;
      float ob = out_b[d];
      float dc = fminf(fmaxf(Dp[d], -2.f), 2.f);
#pragma unroll
      for (int ni = 0; ni < 4; ni++) {
        int l = l0g + ni * 16 + l16;
        float v = acc[mi][ni][r] + ob;
        if (dc != 0.f) v += dc * b2f(xln1b[(size_t)l * 192 + d]);
        size_t idx = ((size_t)bb * Dm + d) * Ln + (l & 4095);
        float nx = xrv[mi][r][ni] + as_ * v;
        xr[idx] = nx;
        tile[(l & 63) * 193 + d] = nx;
      }
    }
  __syncthreads();
  float g0 = g2[lane], g1v = g2[lane + 64], g2v = g2[lane + 128];
  float b0 = bb2[lane], b1v = bb2[lane + 64], b2v = bb2[lane + 128];
  for (int li = wv; li < 64; li += 4) {
    float v0 = tile[li * 193 + lane], v1 = tile[li * 193 + lane + 64], v2 = tile[li * 193 + lane + 128];
    float s  = wave_sum(v0 + v1 + v2);
    float sq = wave_sum(v0 * v0 + v1 * v1 + v2 * v2);
    float m = s * (1.f / 192.f);
    float inv = rsqrtf(sq * (1.f / 192.f) - m * m + 1e-5f);
    size_t base = (size_t)(l0g + li) * Dm;
    xn2[base + lane]       = f2b((v0 - m) * inv * g0 + b0);
    xn2[base + lane + 64]  = f2b((v1 - m) * inv * g1v + b1v);
    xn2[base + lane + 128] = f2b((v2 - m) * inv * g2v + b2v);
  }
}

// ---- K5: MFMA GEMM1, XCD-swizzled flat grid 1536 ---------------------------
// xcd = bid&7; within an XCD the 6 n-blocks of one m-tile are consecutive ->
// A-tile fetched from HBM once per XCD (1.6MB/XCD working set fits 4MB L2).
__global__ __launch_bounds__(256) void k_gemm1(
    const short* __restrict__ xn2, const short* __restrict__ w1b,
    const float* __restrict__ b1h, short* __restrict__ hid) {
  __shared__ __align__(16) short smem[2 * 128 * 72];  // 36.9 KB
  short* As = smem;
  short* Bs = smem + 128 * 72;
  int bid = blockIdx.x;
  int xcd = bid & 7, p = bid >> 3;          // p: 0..191
  int m0 = (xcd * 32 + p / 6) * 128, n0 = (p % 6) * 128;
  int tid = threadIdx.x;
  int lane = tid & 63, l16 = lane & 15, quad = lane >> 4;
  int wm = (tid >> 6) >> 1, wn = (tid >> 6) & 1;
  f32x4 acc[4][4] = {};
  for (int kt = 0; kt < 3; kt++) {
    int kb = kt * 64;
    for (int i = tid; i < 1024; i += 256) {
      int row = i >> 3, c8 = (i & 7) * 8;
      *(float4*)&As[row * 72 + c8] = *(const float4*)&xn2[(size_t)(m0 + row) * 192 + kb + c8];
      *(float4*)&Bs[row * 72 + c8] = *(const float4*)&w1b[(size_t)(n0 + row) * 192 + kb + c8];
    }
    __syncthreads();
#pragma unroll
    for (int ks = 0; ks < 2; ks++) {
      int ko = ks * 32 + quad * 8;
      bf16x8 a[4], b[4];
#pragma unroll
      for (int mi = 0; mi < 4; mi++) a[mi] = *(const bf16x8*)&As[(wm * 64 + mi * 16 + l16) * 72 + ko];
#pragma unroll
      for (int ni = 0; ni < 4; ni++) b[ni] = *(const bf16x8*)&Bs[(wn * 64 + ni * 16 + l16) * 72 + ko];
#pragma unroll
      for (int mi = 0; mi < 4; mi++)
#pragma unroll
        for (int ni = 0; ni < 4; ni++)
          acc[mi][ni] = __builtin_amdgcn_mfma_f32_16x16x32_bf16(a[mi], b[ni], acc[mi][ni], 0, 0, 0);
    }
    __syncthreads();
  }
  short* Cs = smem;  // [128][136] = 34.8 KB, fits
  float bias4[4];
#pragma unroll
  for (int ni = 0; ni < 4; ni++) bias4[ni] = b1h[n0 + wn * 64 + ni * 16 + l16];
#pragma unroll
  for (int mi = 0; mi < 4; mi++)
#pragma unroll
    for (int ni = 0; ni < 4; ni++) {
      int n = wn * 64 + ni * 16 + l16;
#pragma unroll
      for (int r = 0; r < 4; r++) {
        int m = wm * 64 + mi * 16 + quad * 4 + r;
        float v = acc[mi][ni][r] + bias4[ni];
        float g = 0.5f * v * (1.f + erff(v * 0.70710678118f));
        Cs[m * 136 + n] = f2b(g);
      }
    }
  __syncthreads();
  for (int i = tid; i < 2048; i += 256) {
    int m = i >> 4, ch = i & 15;
    *(float4*)&hid[(size_t)(m0 + m) * 768 + n0 + ch * 8] = *(const float4*)&Cs[m * 136 + ch * 8];
  }
}

// ---- K6: MFMA GEMM2, XCD-swizzled flat grid 1024 ---------------------------
// The two d-halves sharing one Ht (hid l-tile) are consecutive on one XCD.
__global__ __launch_bounds__(256) void k_gemm2(
    const short* __restrict__ hid, const short* __restrict__ w2b,
    const float* __restrict__ b2o, const float* __restrict__ xr,
    const float* __restrict__ am, float* __restrict__ out) {
  __shared__ __align__(16) short Wt[96 * 72];
  __shared__ __align__(16) short Ht[64 * 72];
  int bid = blockIdx.x;
  int xcd = bid & 7, p = bid >> 3;          // p: 0..127
  int l0g = (xcd * 64 + (p >> 1)) * 64, d0 = (p & 1) * 96;
  int tid = threadIdx.x;
  int lane = tid & 63, l16 = lane & 15, quad = lane >> 4;
  int wm = (tid >> 6) >> 1, wn = (tid >> 6) & 1;
  f32x4 acc[3][2] = {};
  for (int kt = 0; kt < 12; kt++) {
    int kb = kt * 64;
    for (int i = tid; i < 768; i += 256) {
      int row = i >> 3, c8 = (i & 7) * 8;
      *(float4*)&Wt[row * 72 + c8] = *(const float4*)&w2b[(size_t)(d0 + row) * 768 + kb + c8];
    }
    for (int i = tid; i < 512; i += 256) {
      int row = i >> 3, c8 = (i & 7) * 8;
      *(float4*)&Ht[row * 72 + c8] = *(const float4*)&hid[(size_t)(l0g + row) * 768 + kb + c8];
    }
    __syncthreads();
#pragma unroll
    for (int ks = 0; ks < 2; ks++) {
      int ko = ks * 32 + quad * 8;
      bf16x8 a[3], b[2];
#pragma unroll
      for (int mi = 0; mi < 3; mi++) a[mi] = *(const bf16x8*)&Wt[(wm * 48 + mi * 16 + l16) * 72 + ko];
#pragma unroll
      for (int ni = 0; ni < 2; ni++) b[ni] = *(const bf16x8*)&Ht[(wn * 32 + ni * 16 + l16) * 72 + ko];
#pragma unroll
      for (int mi = 0; mi < 3; mi++)
#pragma unroll
        for (int ni = 0; ni < 2; ni++)
          acc[mi][ni] = __builtin_amdgcn_mfma_f32_16x16x32_bf16(a[mi], b[ni], acc[mi][ni], 0, 0, 0);
    }
    __syncthreads();
  }
  float alpha = am[0];
#pragma unroll
  for (int mi = 0; mi < 3; mi++)
#pragma unroll
    for (int r = 0; r < 4; r++) {
      int d = d0 + wm * 48 + mi * 16 + quad * 4 + r;
      float bias = b2o[d];
#pragma unroll
      for (int ni = 0; ni < 2; ni++) {
        int lg = l0g + wn * 32 + ni * 16 + l16;
        size_t idx = ((size_t)(lg >> 12) * Dm + d) * Ln + (lg & 4095);
        out[idx] = xr[idx] + alpha * (acc[mi][ni][r] + bias);
      }
    }
}

extern "C" void kernel_launch(void* const* d_in, const int* in_sizes, int n_in,
                              void* d_out, int out_size, void* d_ws, size_t ws_size,
                              hipStream_t stream) {
  (void)in_sizes; (void)n_in; (void)out_size; (void)ws_size;
  const float* x     = (const float*)d_in[0];
  const float* ln1_g = (const float*)d_in[1];
  const float* ln1_b = (const float*)d_in[2];
  const float* ln2_g = (const float*)d_in[3];
  const float* ln2_b = (const float*)d_in[4];
  const float* dw_w  = (const float*)d_in[5];
  const float* bn_g  = (const float*)d_in[6];
  const float* bn_b  = (const float*)d_in[7];
  const float* bn_rm = (const float*)d_in[8];
  const float* bn_rv = (const float*)d_in[9];
  const float* ssm_g = (const float*)d_in[10];
  const float* ssm_b = (const float*)d_in[11];
  const float* xp_w  = (const float*)d_in[12];
  const float* xp_b  = (const float*)d_in[13];
  const float* dt_w  = (const float*)d_in[14];
  const float* dt_b  = (const float*)d_in[15];
  const float* A_log = (const float*)d_in[16];
  const float* B_w   = (const float*)d_in[17];
  const float* C_w   = (const float*)d_in[18];
  const float* Dp    = (const float*)d_in[19];
  const float* out_w = (const float*)d_in[20];
  const float* out_b = (const float*)d_in[21];
  const float* w1    = (const float*)d_in[22];
  const float* b1    = (const float*)d_in[23];
  const float* w2    = (const float*)d_in[24];
  const float* b2    = (const float*)d_in[25];
  const float* a_loc = (const float*)d_in[26];
  const float* a_ssm = (const float*)d_in[27];
  const float* a_mlp = (const float*)d_in[28];

  float* ws = (float*)d_ws;
  short*    xnb   = (short*)ws;                    // [32768,192] bf16
  short*    xln1b = (short*)(ws + 3145728);        // [32768,192] bf16
  float*    aA    = ws + 6291456;                  // [32768,64] f32
  unsigned* bxc   = (unsigned*)(ws + 8388608);     // [32768,64] packed bf16x2
  float*    xr    = ws + 17825792;                 // [8,192,4096] f32
  short*    wb    = (short*)(ws + 24117248);       // bf16 weights
  float*    sums  = ws + 24829952;                 // 131072 f
  float*    carr  = ws + 24961024;                 // 65536 f
  short*    xn2   = (short*)(ws + 25026560);       // [32768,192] bf16
  short*    hid   = (short*)(ws + 28172288);       // [32768,768] bf16
  short*    wcatb = wb;            // [256,192] = dt|B|C|xp rows
  short*    owb   = wb + 49152;    // [192,64]
  short*    w1b   = wb + 61440;    // [768,192]
  short*    w2b   = wb + 208896;   // [192,768]
  float*    out   = (float*)d_out;

  k_prep <<<dim3(64, 9),  256, 0, stream>>>(x, ln1_g, ln1_b, ssm_g, ssm_b, xnb, xln1b,
                                            dt_w, B_w, C_w, xp_w, out_w, w1, w2, wb);
  k_proj <<<dim3(512),    256, 0, stream>>>(xnb, wcatb, dt_b, xp_b, A_log, aA, bxc, sums);
  k_conv <<<dim3(193, 8), 256, 0, stream>>>(x, dw_w, bn_g, bn_b, bn_rm, bn_rv, a_loc, xr,
                                            sums, carr);
  k_out  <<<dim3(512),    256, 0, stream>>>(aA, bxc, carr, owb, out_b, Dp, xln1b,
                                            a_ssm, ln2_g, ln2_b, xr, xn2);
  k_gemm1<<<dim3(1536),   256, 0, stream>>>(xn2, w1b, b1, hid);
  k_gemm2<<<dim3(1024),   256, 0, stream>>>(hid, w2b, b2, xr, a_mlp, out);
}